// Round 5
// baseline (428.078 us; speedup 1.0000x reference)
//
#include <hip/hip_runtime.h>
#include <hip/hip_bf16.h>

#define BB 8
#define CC 64
#define HH 256
#define WW 256

__device__ __forceinline__ unsigned short f2bf(float f) {
    __hip_bfloat16 h = __float2bfloat16(f);   // RNE
    return *reinterpret_cast<unsigned short*>(&h);
}
__device__ __forceinline__ float bf2f(unsigned short u) {
    unsigned int v = ((unsigned int)u) << 16;
    float r;
    __builtin_memcpy(&r, &v, 4);
    return r;
}
__device__ __forceinline__ float bflo(unsigned int u) {   // low ushort -> float
    unsigned int v = u << 16;
    float r; __builtin_memcpy(&r, &v, 4); return r;
}
__device__ __forceinline__ float bfhi(unsigned int u) {   // high ushort -> float
    unsigned int v = u & 0xffff0000u;
    float r; __builtin_memcpy(&r, &v, 4); return r;
}

// ---------------------------------------------------------------------------
// K1: fused 5x5 depthwise (pad 2) + 1x21 horizontal depthwise (pad 10).
// Round-4 counters: DS-pipe-bound (3.7e7 conflict-cycles, 16 waves/CU).
// Fixes:
//  (a) xs LDS uses row-permuted layout phys = (r>>1)+(r&1)*18 with ODD stride
//      (67 float4): the two half-waves of each b128 read (logical rows r, r+2)
//      land on complementary bank halves -> full 32-bank coverage.
//  (b) h-conv via __shfl (ds_bpermute, 4B) from registers: a1 never touches
//      LDS (saves 20 b128 ops/thread + 36KB LDS + the mid barrier).
//      LDS 38.6KB -> 3-4 blocks/CU instead of 2.
// Thread = 2 adjacent rows x 8 cols; 512 threads = 32-row strip.
// ---------------------------------------------------------------------------
__global__ __launch_bounds__(512) void k1_local_h(
        const float* __restrict__ x, const float* __restrict__ lw,
        const float* __restrict__ hw, unsigned short* __restrict__ a2out) {
    const int strip = blockIdx.x;          // 0..7
    const int bc    = blockIdx.y;          // 0..511
    const int c     = bc & (CC - 1);
    const int y0    = strip * 32;
    const int tid   = threadIdx.x;

    // logical rows 0..35 = x rows y0-2 .. y0+33; group g covers gx = 4g-4..4g-1
    // phys row = (r>>1) + (r&1)*18; stride 67 float4 (odd -> complementary halves)
    __shared__ float4 xs4[36][67];         // 38,592 B

    const float* xbase = x + (size_t)bc * (HH * WW);

    for (int i = tid; i < 36 * 66; i += 512) {
        int rr = i / 66, g = i - rr * 66;
        int gy = y0 - 2 + rr;
        float4 v = make_float4(0.f, 0.f, 0.f, 0.f);
        if (gy >= 0 && gy < HH && g >= 1 && g <= 64)
            v = *reinterpret_cast<const float4*>(xbase + (size_t)gy * WW + 4 * (g - 1));
        xs4[(rr >> 1) + (rr & 1) * 18][g] = v;
    }
    __syncthreads();

    const int cg = tid & 31;               // 8-col group: cols 8cg..8cg+7
    const int rp = tid >> 5;               // row pair: rows y0+2rp, y0+2rp+1
    const float* lwc = lw + c * 25;        // block-uniform -> s_load

    float acc0[8], acc1[8];
    #pragma unroll
    for (int j = 0; j < 8; ++j) { acc0[j] = 0.f; acc1[j] = 0.f; }

    // 6 logical xs rows (2rp..2rp+5) feed both output rows (5 each, offset 1).
    // f idx: xc = 8cg-4+f; tap xc = 8cg+j+kx-2 -> f = j+kx+2 in [2,13]
    #pragma unroll
    for (int t = 0; t < 6; ++t) {
        const int pr = 0 + (t >> 1) + (t & 1) * 18;   // + rp below (runtime)
        float4 g0 = xs4[rp + pr][2 * cg + 0];
        float4 g1 = xs4[rp + pr][2 * cg + 1];
        float4 g2 = xs4[rp + pr][2 * cg + 2];
        float4 g3 = xs4[rp + pr][2 * cg + 3];
        float f[16] = {g0.x, g0.y, g0.z, g0.w, g1.x, g1.y, g1.z, g1.w,
                       g2.x, g2.y, g2.z, g2.w, g3.x, g3.y, g3.z, g3.w};
        if (t < 5) {
            #pragma unroll
            for (int kx = 0; kx < 5; ++kx) {
                float wv = lwc[t * 5 + kx];
                #pragma unroll
                for (int j = 0; j < 8; ++j)
                    acc0[j] = fmaf(wv, f[j + kx + 2], acc0[j]);
            }
        }
        if (t >= 1) {
            #pragma unroll
            for (int kx = 0; kx < 5; ++kx) {
                float wv = lwc[(t - 1) * 5 + kx];
                #pragma unroll
                for (int j = 0; j < 8; ++j)
                    acc1[j] = fmaf(wv, f[j + kx + 2], acc1[j]);
            }
        }
    }

    // h-conv fully in registers: window col 8cg-10+i, i=0..27.
    // own cols -> [10..17]; lane cg-1 -> [2..9]; cg-2 -> [0..1];
    // cg+1 -> [18..25]; cg+2 -> [26..27].  Out-of-image taps masked to 0
    // (mask condition == source-lane-validity condition, so cross-half
    // garbage from shfl at the wave edge is always masked).
    const float* hwc = hw + c * 21;
    #pragma unroll
    for (int row = 0; row < 2; ++row) {
        float a[8];
        #pragma unroll
        for (int j = 0; j < 8; ++j) a[j] = row ? acc1[j] : acc0[j];

        float w28[28];
        w28[0] = __shfl_up(a[6], 2, 64);
        w28[1] = __shfl_up(a[7], 2, 64);
        #pragma unroll
        for (int j = 0; j < 8; ++j) w28[2 + j]  = __shfl_up(a[j], 1, 64);
        #pragma unroll
        for (int j = 0; j < 8; ++j) w28[10 + j] = a[j];
        #pragma unroll
        for (int j = 0; j < 8; ++j) w28[18 + j] = __shfl_down(a[j], 1, 64);
        w28[26] = __shfl_down(a[0], 2, 64);
        w28[27] = __shfl_down(a[1], 2, 64);

        if (cg < 2)  { w28[0] = 0.f; w28[1] = 0.f; }
        if (cg < 1)  {
            #pragma unroll
            for (int j = 0; j < 8; ++j) w28[2 + j] = 0.f;
        }
        if (cg > 30) {
            #pragma unroll
            for (int j = 0; j < 8; ++j) w28[18 + j] = 0.f;
        }
        if (cg > 29) { w28[26] = 0.f; w28[27] = 0.f; }

        float o[8];
        #pragma unroll
        for (int j = 0; j < 8; ++j) o[j] = 0.f;
        #pragma unroll
        for (int k = 0; k < 21; ++k) {
            float wv = hwc[k];
            #pragma unroll
            for (int j = 0; j < 8; ++j)
                o[j] = fmaf(wv, w28[j + k], o[j]);   // tap col 8cg+j+k-10
        }

        unsigned short* dst = a2out + (size_t)(bc * HH + y0 + 2 * rp + row) * WW + 8 * cg;
        uint4 pk;
        pk.x = (unsigned)f2bf(o[0]) | ((unsigned)f2bf(o[1]) << 16);
        pk.y = (unsigned)f2bf(o[2]) | ((unsigned)f2bf(o[3]) << 16);
        pk.z = (unsigned)f2bf(o[4]) | ((unsigned)f2bf(o[5]) << 16);
        pk.w = (unsigned)f2bf(o[6]) | ((unsigned)f2bf(o[7]) << 16);
        *reinterpret_cast<uint4*>(dst) = pk;
    }
}

// ---------------------------------------------------------------------------
// K2a: 21x1 vertical depthwise (pad 10), gather through LDS.
// (unchanged from round 4)
// ---------------------------------------------------------------------------
__global__ __launch_bounds__(256) void k2a_v(
        const unsigned short* __restrict__ a2, const float* __restrict__ vw,
        unsigned short* __restrict__ a3) {
    const int bx    = blockIdx.x;          // 0..7
    const int strip = bx >> 1;             // 0..3 -> y0
    const int x0    = (bx & 1) * 128;      // col half
    const int bc    = blockIdx.y;
    const int c     = bc & (CC - 1);
    const int y0    = strip * 64;
    const int tid   = threadIdx.x;

    __shared__ unsigned short lds[84][128];   // 21504 B

    const unsigned short* sbase = a2 + (size_t)bc * (HH * WW) + x0;
    for (int i = tid; i < 84 * 16; i += 256) {
        int row = i >> 4, g = i & 15;
        int gy = y0 - 10 + row;
        uint4 v = make_uint4(0u, 0u, 0u, 0u);
        if (gy >= 0 && gy < HH)
            v = *reinterpret_cast<const uint4*>(sbase + (size_t)gy * WW + g * 8);
        *reinterpret_cast<uint4*>(&lds[row][g * 8]) = v;
    }
    __syncthreads();

    const float* vwc = vw + c * 21;        // block-uniform -> s_load
    float w[21];
    #pragma unroll
    for (int k = 0; k < 21; ++k) w[k] = vwc[k];

    const int cg = tid & 15;               // cols x0+8cg..x0+8cg+7
    const int rg = tid >> 4;               // rows y0+4rg..y0+4rg+3
    unsigned short* dst = a3 + (size_t)bc * (HH * WW)
                        + (size_t)(y0 + rg * 4) * WW + x0 + cg * 8;

    #pragma unroll 1
    for (int i = 0; i < 4; ++i) {
        float s0 = 0.f, s1 = 0.f, s2 = 0.f, s3 = 0.f;
        float s4 = 0.f, s5 = 0.f, s6 = 0.f, s7 = 0.f;
        #pragma unroll
        for (int k = 0; k < 21; ++k) {
            uint4 u = *reinterpret_cast<const uint4*>(&lds[rg * 4 + i + k][cg * 8]);
            float wk = w[k];
            s0 = fmaf(wk, bflo(u.x), s0); s1 = fmaf(wk, bfhi(u.x), s1);
            s2 = fmaf(wk, bflo(u.y), s2); s3 = fmaf(wk, bfhi(u.y), s3);
            s4 = fmaf(wk, bflo(u.z), s4); s5 = fmaf(wk, bfhi(u.z), s5);
            s6 = fmaf(wk, bflo(u.w), s6); s7 = fmaf(wk, bfhi(u.w), s7);
        }
        uint4 o;
        o.x = (unsigned int)f2bf(s0) | ((unsigned int)f2bf(s1) << 16);
        o.y = (unsigned int)f2bf(s2) | ((unsigned int)f2bf(s3) << 16);
        o.z = (unsigned int)f2bf(s4) | ((unsigned int)f2bf(s5) << 16);
        o.w = (unsigned int)f2bf(s6) | ((unsigned int)f2bf(s7) << 16);
        *reinterpret_cast<uint4*>(dst + (size_t)i * WW) = o;
    }
}

// ---------------------------------------------------------------------------
// K2b: 1x1 pointwise (64x64) + BN + sigmoid gate.
// (unchanged from round 4)
// ---------------------------------------------------------------------------
__global__ __launch_bounds__(512, 4) void k2b_pw(
        const unsigned short* __restrict__ a3, const float* __restrict__ x,
        const float* __restrict__ pw, const float* __restrict__ gamma,
        const float* __restrict__ beta, const float* __restrict__ mean,
        const float* __restrict__ var, float* __restrict__ out) {
    const int y   = blockIdx.x;
    const int b   = blockIdx.y;
    const int tid = threadIdx.x;

    __shared__ unsigned short a3s[64][256];   // 32 KB

    const unsigned short* abase = a3 + ((size_t)b * CC * HH + y) * WW;
    for (int i = tid; i < 64 * 64; i += 512) {
        int ci = i >> 6, q = (i & 63) << 2;
        ushort4 v = *reinterpret_cast<const ushort4*>(abase + (size_t)ci * HH * WW + q);
        *reinterpret_cast<ushort4*>(&a3s[ci][q]) = v;
    }
    __syncthreads();

    const int wu = __builtin_amdgcn_readfirstlane(tid >> 6);  // wave-uniform, 0..7
    const int l  = tid & 63;

    float acc[32];
    #pragma unroll
    for (int i = 0; i < 32; ++i) acc[i] = 0.f;

    const float* wbase = pw + (size_t)(wu * 8) * 64;   // 8 co per wave

    #pragma unroll
    for (int ch = 0; ch < 16; ++ch) {
        ushort4 q0 = *reinterpret_cast<const ushort4*>(&a3s[4 * ch + 0][l << 2]);
        ushort4 q1 = *reinterpret_cast<const ushort4*>(&a3s[4 * ch + 1][l << 2]);
        ushort4 q2 = *reinterpret_cast<const ushort4*>(&a3s[4 * ch + 2][l << 2]);
        ushort4 q3 = *reinterpret_cast<const ushort4*>(&a3s[4 * ch + 3][l << 2]);
        float p0x = bf2f(q0.x), p0y = bf2f(q0.y), p0z = bf2f(q0.z), p0w = bf2f(q0.w);
        float p1x = bf2f(q1.x), p1y = bf2f(q1.y), p1z = bf2f(q1.z), p1w = bf2f(q1.w);
        float p2x = bf2f(q2.x), p2y = bf2f(q2.y), p2z = bf2f(q2.z), p2w = bf2f(q2.w);
        float p3x = bf2f(q3.x), p3y = bf2f(q3.y), p3z = bf2f(q3.z), p3w = bf2f(q3.w);
        #pragma unroll
        for (int j = 0; j < 8; ++j) {
            float4 w4 = *reinterpret_cast<const float4*>(wbase + (size_t)j * 64 + 4 * ch);
            acc[j * 4 + 0] = fmaf(w4.x, p0x, acc[j * 4 + 0]);
            acc[j * 4 + 0] = fmaf(w4.y, p1x, acc[j * 4 + 0]);
            acc[j * 4 + 0] = fmaf(w4.z, p2x, acc[j * 4 + 0]);
            acc[j * 4 + 0] = fmaf(w4.w, p3x, acc[j * 4 + 0]);
            acc[j * 4 + 1] = fmaf(w4.x, p0y, acc[j * 4 + 1]);
            acc[j * 4 + 1] = fmaf(w4.y, p1y, acc[j * 4 + 1]);
            acc[j * 4 + 1] = fmaf(w4.z, p2y, acc[j * 4 + 1]);
            acc[j * 4 + 1] = fmaf(w4.w, p3y, acc[j * 4 + 1]);
            acc[j * 4 + 2] = fmaf(w4.x, p0z, acc[j * 4 + 2]);
            acc[j * 4 + 2] = fmaf(w4.y, p1z, acc[j * 4 + 2]);
            acc[j * 4 + 2] = fmaf(w4.z, p2z, acc[j * 4 + 2]);
            acc[j * 4 + 2] = fmaf(w4.w, p3z, acc[j * 4 + 2]);
            acc[j * 4 + 3] = fmaf(w4.x, p0w, acc[j * 4 + 3]);
            acc[j * 4 + 3] = fmaf(w4.y, p1w, acc[j * 4 + 3]);
            acc[j * 4 + 3] = fmaf(w4.z, p2w, acc[j * 4 + 3]);
            acc[j * 4 + 3] = fmaf(w4.w, p3w, acc[j * 4 + 3]);
        }
    }

    #pragma unroll
    for (int j = 0; j < 8; ++j) {
        int co = wu * 8 + j;
        float inv = gamma[co] * rsqrtf(var[co] + 1e-5f);
        float sh  = beta[co] - mean[co] * inv;
        size_t off = (((size_t)b * CC + co) * HH + y) * WW + (l << 2);
        float4 xv = *reinterpret_cast<const float4*>(x + off);
        float4 r;
        float a;
        a = acc[j * 4 + 0] * inv + sh; r.x = xv.x / (1.f + __expf(-a));
        a = acc[j * 4 + 1] * inv + sh; r.y = xv.y / (1.f + __expf(-a));
        a = acc[j * 4 + 2] * inv + sh; r.z = xv.z / (1.f + __expf(-a));
        a = acc[j * 4 + 3] * inv + sh; r.w = xv.w / (1.f + __expf(-a));
        *reinterpret_cast<float4*>(out + off) = r;
    }
}

extern "C" void kernel_launch(void* const* d_in, const int* in_sizes, int n_in,
                              void* d_out, int out_size, void* d_ws, size_t ws_size,
                              hipStream_t stream) {
    const float* x     = (const float*)d_in[0];
    const float* lw    = (const float*)d_in[1];
    const float* hw    = (const float*)d_in[2];
    const float* vw    = (const float*)d_in[3];
    const float* pw    = (const float*)d_in[4];
    const float* gamma = (const float*)d_in[5];
    const float* beta  = (const float*)d_in[6];
    const float* mean  = (const float*)d_in[7];
    const float* var   = (const float*)d_in[8];
    float* out = (float*)d_out;

    // ws: attn2 (bf16) + attn3 (bf16) = 2 * 64 MiB = 128 MiB
    unsigned short* ws1 = (unsigned short*)d_ws;
    unsigned short* ws2 = ws1 + (size_t)BB * CC * HH * WW;

    k1_local_h<<<dim3(HH / 32, BB * CC), 512, 0, stream>>>(x, lw, hw, ws1);
    k2a_v<<<dim3(8, BB * CC), 256, 0, stream>>>(ws1, vw, ws2);
    k2b_pw<<<dim3(HH, BB), 512, 0, stream>>>(ws2, x, pw, gamma, beta, mean, var, out);
}

// Round 7
// 424.149 us; speedup vs baseline: 1.0093x; 1.0093x over previous
//
#include <hip/hip_runtime.h>
#include <hip/hip_bf16.h>

#define BB 8
#define CC 64
#define HH 256
#define WW 256

__device__ __forceinline__ unsigned short f2bf(float f) {
    __hip_bfloat16 h = __float2bfloat16(f);   // RNE
    return *reinterpret_cast<unsigned short*>(&h);
}
__device__ __forceinline__ float bf2f(unsigned short u) {
    unsigned int v = ((unsigned int)u) << 16;
    float r;
    __builtin_memcpy(&r, &v, 4);
    return r;
}
__device__ __forceinline__ float bflo(unsigned int u) {   // low ushort -> float
    unsigned int v = u << 16;
    float r; __builtin_memcpy(&r, &v, 4); return r;
}
__device__ __forceinline__ float bfhi(unsigned int u) {   // high ushort -> float
    unsigned int v = u & 0xffff0000u;
    float r; __builtin_memcpy(&r, &v, 4); return r;
}

// ---------------------------------------------------------------------------
// K1 v3: fused 5x5 depthwise (pad 2) + 1x21 horizontal depthwise (pad 10).
// R4/R5 counters: DS-pipe-bound; lane-stride-32B b128 reads hit only 16/32
// banks (structural 2x).  Redesign:
//   - thread = ONE float4 of cols (4cg..4cg+3) x 8 rows -> every LDS op is
//     lane-stride-16B = uniform banks, conflict-free by construction.
//   - 5x5 inputs come straight from GLOBAL (3 predicated dwordx4 per input
//     row; re-reads are L1/L2 hits - memory was at 13% of peak).  No xs LDS.
//   - LDS holds ONLY the h-conv exchange: per-wave 2-row buffer (9 KB/block
//     vs 39-74 KB) -> high occupancy.  One __syncthreads per row-pair
//     (write->read compiler-ordering; buffers are wave-private).
// FMA order per output identical to R4 -> bitwise-identical a2 output.
// 256 threads = 4 waves; wave rw owns rows y0+8rw..y0+8rw+7 (32-row strip).
// (Resubmitted unchanged after round-6 infra failure.)
// ---------------------------------------------------------------------------
__global__ __launch_bounds__(256) void k1_local_h(
        const float* __restrict__ x, const float* __restrict__ lw,
        const float* __restrict__ hw, unsigned short* __restrict__ a2out) {
    const int strip = blockIdx.x;          // 0..7
    const int bc    = blockIdx.y;          // 0..511
    const int c     = bc & (CC - 1);
    const int y0    = strip * 32;
    const int tid   = threadIdx.x;
    const int cg    = tid & 63;            // col group: cols 4cg..4cg+3
    const int rw    = tid >> 6;            // wave id 0..3

    // per-wave double row buffer: phys group p holds 5x5-out group G = p-3
    // (cols 4G..4G+3); p 0..2 / 67..69 are zero pads for the h-conv halo.
    __shared__ float4 arow[4][2][70];      // 8960 B

    // zero pads of this wave's two row slots (lanes 0..11)
    if (cg < 12) {
        int rr = cg >= 6 ? 1 : 0;
        int g6 = cg - 6 * rr;
        arow[rw][rr][g6 < 3 ? g6 : 64 + g6] = make_float4(0.f, 0.f, 0.f, 0.f);
    }
    // ordered before first read by the loop's __syncthreads.

    const float* lwc = lw + c * 25;        // block-uniform -> s_load
    const float* hwc = hw + c * 21;
    const float* xbase = x + (size_t)bc * (HH * WW);

    #pragma unroll 1
    for (int pr = 0; pr < 4; ++pr) {
        const int yy = y0 + 8 * rw + 2 * pr;   // output rows yy, yy+1
        float acc0[4] = {0.f, 0.f, 0.f, 0.f};
        float acc1[4] = {0.f, 0.f, 0.f, 0.f};

        // 6 input rows feed both output rows (5 each, offset 1).
        // f[] covers cols 4cg-4 .. 4cg+7; tap col 4cg+j+kx-2 -> f[j+kx+2]
        #pragma unroll
        for (int t = 0; t < 6; ++t) {
            const int gy = yy - 2 + t;         // wave-uniform -> scalar branch
            float4 A = make_float4(0.f, 0.f, 0.f, 0.f);
            float4 B = A, C = A;
            if (gy >= 0 && gy < HH) {
                const float* rp_ = xbase + (size_t)gy * WW + 4 * cg;
                if (cg > 0)  A = *reinterpret_cast<const float4*>(rp_ - 4);
                B = *reinterpret_cast<const float4*>(rp_);
                if (cg < 63) C = *reinterpret_cast<const float4*>(rp_ + 4);
            }
            float f[12] = {A.x, A.y, A.z, A.w, B.x, B.y, B.z, B.w,
                           C.x, C.y, C.z, C.w};
            if (t < 5) {
                #pragma unroll
                for (int kx = 0; kx < 5; ++kx) {
                    float wv = lwc[t * 5 + kx];
                    #pragma unroll
                    for (int j = 0; j < 4; ++j)
                        acc0[j] = fmaf(wv, f[j + kx + 2], acc0[j]);
                }
            }
            if (t >= 1) {
                #pragma unroll
                for (int kx = 0; kx < 5; ++kx) {
                    float wv = lwc[(t - 1) * 5 + kx];
                    #pragma unroll
                    for (int j = 0; j < 4; ++j)
                        acc1[j] = fmaf(wv, f[j + kx + 2], acc1[j]);
                }
            }
        }

        // exchange via wave-private LDS rows (lane-stride-16B writes)
        arow[rw][0][cg + 3] = make_float4(acc0[0], acc0[1], acc0[2], acc0[3]);
        arow[rw][1][cg + 3] = make_float4(acc1[0], acc1[1], acc1[2], acc1[3]);
        __syncthreads();   // compiler-ordering fence for the cross-lane RAW

        #pragma unroll
        for (int row = 0; row < 2; ++row) {
            // window fw[f] = col 4cg-12+f, f=0..27 (7 stride-16B b128 reads)
            float fw[28];
            #pragma unroll
            for (int i2 = 0; i2 < 7; ++i2) {
                float4 g = arow[rw][row][cg + i2];
                fw[4 * i2 + 0] = g.x; fw[4 * i2 + 1] = g.y;
                fw[4 * i2 + 2] = g.z; fw[4 * i2 + 3] = g.w;
            }
            float o[4] = {0.f, 0.f, 0.f, 0.f};
            #pragma unroll
            for (int k = 0; k < 21; ++k) {
                float wv = hwc[k];
                #pragma unroll
                for (int j = 0; j < 4; ++j)
                    o[j] = fmaf(wv, fw[j + k + 2], o[j]);  // tap col 4cg+j+k-10
            }
            unsigned short* dst =
                a2out + (size_t)(bc * HH + yy + row) * WW + 4 * cg;
            ushort4 pk;
            pk.x = f2bf(o[0]); pk.y = f2bf(o[1]);
            pk.z = f2bf(o[2]); pk.w = f2bf(o[3]);
            *reinterpret_cast<ushort4*>(dst) = pk;
        }
        // next iteration's writes alias this iteration's reads per-lane
        // (p = cg+3 is within cg..cg+6) -> compiler keeps order; DS pipe is
        // in-order within a wave; buffers are wave-private -> safe.
    }
}

// ---------------------------------------------------------------------------
// K2a: 21x1 vertical depthwise (pad 10), gather through LDS.
// (unchanged)
// ---------------------------------------------------------------------------
__global__ __launch_bounds__(256) void k2a_v(
        const unsigned short* __restrict__ a2, const float* __restrict__ vw,
        unsigned short* __restrict__ a3) {
    const int bx    = blockIdx.x;          // 0..7
    const int strip = bx >> 1;             // 0..3 -> y0
    const int x0    = (bx & 1) * 128;      // col half
    const int bc    = blockIdx.y;
    const int c     = bc & (CC - 1);
    const int y0    = strip * 64;
    const int tid   = threadIdx.x;

    __shared__ unsigned short lds[84][128];   // 21504 B

    const unsigned short* sbase = a2 + (size_t)bc * (HH * WW) + x0;
    for (int i = tid; i < 84 * 16; i += 256) {
        int row = i >> 4, g = i & 15;
        int gy = y0 - 10 + row;
        uint4 v = make_uint4(0u, 0u, 0u, 0u);
        if (gy >= 0 && gy < HH)
            v = *reinterpret_cast<const uint4*>(sbase + (size_t)gy * WW + g * 8);
        *reinterpret_cast<uint4*>(&lds[row][g * 8]) = v;
    }
    __syncthreads();

    const float* vwc = vw + c * 21;        // block-uniform -> s_load
    float w[21];
    #pragma unroll
    for (int k = 0; k < 21; ++k) w[k] = vwc[k];

    const int cg = tid & 15;               // cols x0+8cg..x0+8cg+7
    const int rg = tid >> 4;               // rows y0+4rg..y0+4rg+3
    unsigned short* dst = a3 + (size_t)bc * (HH * WW)
                        + (size_t)(y0 + rg * 4) * WW + x0 + cg * 8;

    #pragma unroll 1
    for (int i = 0; i < 4; ++i) {
        float s0 = 0.f, s1 = 0.f, s2 = 0.f, s3 = 0.f;
        float s4 = 0.f, s5 = 0.f, s6 = 0.f, s7 = 0.f;
        #pragma unroll
        for (int k = 0; k < 21; ++k) {
            uint4 u = *reinterpret_cast<const uint4*>(&lds[rg * 4 + i + k][cg * 8]);
            float wk = w[k];
            s0 = fmaf(wk, bflo(u.x), s0); s1 = fmaf(wk, bfhi(u.x), s1);
            s2 = fmaf(wk, bflo(u.y), s2); s3 = fmaf(wk, bfhi(u.y), s3);
            s4 = fmaf(wk, bflo(u.z), s4); s5 = fmaf(wk, bfhi(u.z), s5);
            s6 = fmaf(wk, bflo(u.w), s6); s7 = fmaf(wk, bfhi(u.w), s7);
        }
        uint4 o;
        o.x = (unsigned int)f2bf(s0) | ((unsigned int)f2bf(s1) << 16);
        o.y = (unsigned int)f2bf(s2) | ((unsigned int)f2bf(s3) << 16);
        o.z = (unsigned int)f2bf(s4) | ((unsigned int)f2bf(s5) << 16);
        o.w = (unsigned int)f2bf(s6) | ((unsigned int)f2bf(s7) << 16);
        *reinterpret_cast<uint4*>(dst + (size_t)i * WW) = o;
    }
}

// ---------------------------------------------------------------------------
// K2b: 1x1 pointwise (64x64) + BN + sigmoid gate.
// (unchanged)
// ---------------------------------------------------------------------------
__global__ __launch_bounds__(512, 4) void k2b_pw(
        const unsigned short* __restrict__ a3, const float* __restrict__ x,
        const float* __restrict__ pw, const float* __restrict__ gamma,
        const float* __restrict__ beta, const float* __restrict__ mean,
        const float* __restrict__ var, float* __restrict__ out) {
    const int y   = blockIdx.x;
    const int b   = blockIdx.y;
    const int tid = threadIdx.x;

    __shared__ unsigned short a3s[64][256];   // 32 KB

    const unsigned short* abase = a3 + ((size_t)b * CC * HH + y) * WW;
    for (int i = tid; i < 64 * 64; i += 512) {
        int ci = i >> 6, q = (i & 63) << 2;
        ushort4 v = *reinterpret_cast<const ushort4*>(abase + (size_t)ci * HH * WW + q);
        *reinterpret_cast<ushort4*>(&a3s[ci][q]) = v;
    }
    __syncthreads();

    const int wu = __builtin_amdgcn_readfirstlane(tid >> 6);  // wave-uniform, 0..7
    const int l  = tid & 63;

    float acc[32];
    #pragma unroll
    for (int i = 0; i < 32; ++i) acc[i] = 0.f;

    const float* wbase = pw + (size_t)(wu * 8) * 64;   // 8 co per wave

    #pragma unroll
    for (int ch = 0; ch < 16; ++ch) {
        ushort4 q0 = *reinterpret_cast<const ushort4*>(&a3s[4 * ch + 0][l << 2]);
        ushort4 q1 = *reinterpret_cast<const ushort4*>(&a3s[4 * ch + 1][l << 2]);
        ushort4 q2 = *reinterpret_cast<const ushort4*>(&a3s[4 * ch + 2][l << 2]);
        ushort4 q3 = *reinterpret_cast<const ushort4*>(&a3s[4 * ch + 3][l << 2]);
        float p0x = bf2f(q0.x), p0y = bf2f(q0.y), p0z = bf2f(q0.z), p0w = bf2f(q0.w);
        float p1x = bf2f(q1.x), p1y = bf2f(q1.y), p1z = bf2f(q1.z), p1w = bf2f(q1.w);
        float p2x = bf2f(q2.x), p2y = bf2f(q2.y), p2z = bf2f(q2.z), p2w = bf2f(q2.w);
        float p3x = bf2f(q3.x), p3y = bf2f(q3.y), p3z = bf2f(q3.z), p3w = bf2f(q3.w);
        #pragma unroll
        for (int j = 0; j < 8; ++j) {
            float4 w4 = *reinterpret_cast<const float4*>(wbase + (size_t)j * 64 + 4 * ch);
            acc[j * 4 + 0] = fmaf(w4.x, p0x, acc[j * 4 + 0]);
            acc[j * 4 + 0] = fmaf(w4.y, p1x, acc[j * 4 + 0]);
            acc[j * 4 + 0] = fmaf(w4.z, p2x, acc[j * 4 + 0]);
            acc[j * 4 + 0] = fmaf(w4.w, p3x, acc[j * 4 + 0]);
            acc[j * 4 + 1] = fmaf(w4.x, p0y, acc[j * 4 + 1]);
            acc[j * 4 + 1] = fmaf(w4.y, p1y, acc[j * 4 + 1]);
            acc[j * 4 + 1] = fmaf(w4.z, p2y, acc[j * 4 + 1]);
            acc[j * 4 + 1] = fmaf(w4.w, p3y, acc[j * 4 + 1]);
            acc[j * 4 + 2] = fmaf(w4.x, p0z, acc[j * 4 + 2]);
            acc[j * 4 + 2] = fmaf(w4.y, p1z, acc[j * 4 + 2]);
            acc[j * 4 + 2] = fmaf(w4.z, p2z, acc[j * 4 + 2]);
            acc[j * 4 + 2] = fmaf(w4.w, p3z, acc[j * 4 + 2]);
            acc[j * 4 + 3] = fmaf(w4.x, p0w, acc[j * 4 + 3]);
            acc[j * 4 + 3] = fmaf(w4.y, p1w, acc[j * 4 + 3]);
            acc[j * 4 + 3] = fmaf(w4.z, p2w, acc[j * 4 + 3]);
            acc[j * 4 + 3] = fmaf(w4.w, p3w, acc[j * 4 + 3]);
        }
    }

    #pragma unroll
    for (int j = 0; j < 8; ++j) {
        int co = wu * 8 + j;
        float inv = gamma[co] * rsqrtf(var[co] + 1e-5f);
        float sh  = beta[co] - mean[co] * inv;
        size_t off = (((size_t)b * CC + co) * HH + y) * WW + (l << 2);
        float4 xv = *reinterpret_cast<const float4*>(x + off);
        float4 r;
        float a;
        a = acc[j * 4 + 0] * inv + sh; r.x = xv.x / (1.f + __expf(-a));
        a = acc[j * 4 + 1] * inv + sh; r.y = xv.y / (1.f + __expf(-a));
        a = acc[j * 4 + 2] * inv + sh; r.z = xv.z / (1.f + __expf(-a));
        a = acc[j * 4 + 3] * inv + sh; r.w = xv.w / (1.f + __expf(-a));
        *reinterpret_cast<float4*>(out + off) = r;
    }
}

extern "C" void kernel_launch(void* const* d_in, const int* in_sizes, int n_in,
                              void* d_out, int out_size, void* d_ws, size_t ws_size,
                              hipStream_t stream) {
    const float* x     = (const float*)d_in[0];
    const float* lw    = (const float*)d_in[1];
    const float* hw    = (const float*)d_in[2];
    const float* vw    = (const float*)d_in[3];
    const float* pw    = (const float*)d_in[4];
    const float* gamma = (const float*)d_in[5];
    const float* beta  = (const float*)d_in[6];
    const float* mean  = (const float*)d_in[7];
    const float* var   = (const float*)d_in[8];
    float* out = (float*)d_out;

    // ws: attn2 (bf16) + attn3 (bf16) = 2 * 64 MiB = 128 MiB
    unsigned short* ws1 = (unsigned short*)d_ws;
    unsigned short* ws2 = ws1 + (size_t)BB * CC * HH * WW;

    k1_local_h<<<dim3(HH / 32, BB * CC), 256, 0, stream>>>(x, lw, hw, ws1);
    k2a_v<<<dim3(8, BB * CC), 256, 0, stream>>>(ws1, vw, ws2);
    k2b_pw<<<dim3(HH, BB), 512, 0, stream>>>(ws2, x, pw, gamma, beta, mean, var, out);
}